// Round 6
// baseline (362.094 us; speedup 1.0000x reference)
//
#include <hip/hip_runtime.h>
#include <stdint.h>

// Segment layout (elements in each battle row of 10451 floats):
//  player 9 @0 | status 86 @9 | pinfo 8 @95 | 13 x card(740) @103 | potions 43 @9723
//  | relics 180 @9766 | 5 x monster(101) @9946
// Output row (542 floats): player4 @0 | status16 @4 | pinfo2 @20 | cards 13*32 @22
//  | potions8 @438 | relics16 @446 | monsters 5*16 @462
//
// Card path (92% of bytes): persistent blocks, 16 battle rows each, LDS
// double-buffer (2 x 9728 floats). Per iteration: issue row r+1's 38 DMA
// rounds, s_waitcnt vmcnt(38) (drain row r only, keep r+1 in flight),
// barrier, compute row r while r+1 streams -> HBM never idles (fixes the
// phase-locked stage/compute duty cycle of the one-shot R5 structure).
// 4 waves = (n-half, K-half); K-halves reduced via small LDS scratch.
// Small segments (8%): R5 windowed-LDS path, bids interleaved 5:4 among card
// bids so their latency-bound chunks fill HBM slack instead of a serial tail.

typedef __attribute__((ext_vector_type(8))) short short8;
typedef __attribute__((ext_vector_type(4))) float f32x4;

__device__ inline unsigned short f2bf(float f) {
  union { float f; uint32_t u; } v; v.f = f;
  uint32_t r = v.u + 0x7FFFu + ((v.u >> 16) & 1u);   // round-to-nearest-even
  return (unsigned short)(r >> 16);
}

__device__ inline void gload_dw(const float* g, float* lds) {
  __builtin_amdgcn_global_load_lds(
      (const __attribute__((address_space(1))) void*)g,
      (__attribute__((address_space(3))) void*)lds, 4, 0, 0);
}

// Card W -> fragment-interleaved bf16: dword idx = cs*512 + wn*256 + kg*64 + rl*4 + d
// where cs (0..23) covers k = cs*32 + kg*8 + d*2; n = wn*16 + rl. Zero-padded
// beyond k=740. 12288 dwords = 48 KB.
__global__ __launch_bounds__(256) void pack_w(const float* __restrict__ Wc,
                                              uint32_t* __restrict__ wout) {
  int el = blockIdx.x * 256 + threadIdx.x;
  if (el >= 12288) return;
  int d  = el & 3;
  int rl = (el >> 2) & 15;
  int kg = (el >> 6) & 3;
  int wn = (el >> 8) & 1;
  int cs = el >> 9;
  int n  = wn * 16 + rl;
  int k  = cs * 32 + kg * 8 + d * 2;
  float v0 = (k     < 740) ? Wc[n * 740 + k]     : 0.0f;
  float v1 = (k + 1 < 740) ? Wc[n * 740 + k + 1] : 0.0f;
  wout[el] = (uint32_t)f2bf(v0) | ((uint32_t)f2bf(v1) << 16);
}

__global__ __launch_bounds__(256, 2) void seg_gemm(
    const float* __restrict__ battle,
    const float* __restrict__ Wplayer, const float* __restrict__ Wstatus,
    const float* __restrict__ Wpinfo,  const float* __restrict__ Wpotions,
    const float* __restrict__ Wrelics, const float* __restrict__ Wmonster,
    const uint32_t* __restrict__ wpack2,
    float* __restrict__ out, const float* __restrict__ zpage)
{
  // card: dbuf 2*9728 + wred 512 = 19968 floats (79872 B); small: a 4096 + w 1024
  __shared__ float shm[19968];
  const int bid  = blockIdx.x;
  const int t    = threadIdx.x;
  const int lane = t & 63;
  const int wv   = t >> 6;
  const int rl   = lane & 15;
  const int kg   = lane >> 4;

  const int g9 = bid / 9, r9 = bid - g9 * 9;   // 512 groups of 9: 5 small + 4 card

  if (r9 >= 5) {
    // ======================= card path (persistent, 16 rows) =======================
    const int cb   = g9 * 4 + (r9 - 5);        // 0..2047
    const int row0 = cb * 16;
    const int wn   = wv & 1;                   // n-half
    const int wk   = wv >> 1;                  // K-half
    const uint32_t abase = (rl < 13) ? (uint32_t)(rl * 740) : 0u;
    float* wred = &shm[19456];

    auto stagec = [&](int r, int pb) {
      const uint32_t g = (uint32_t)(row0 + r) * 10451u + 103u;
      float* dst = &shm[pb * 9728];
      #pragma unroll
      for (int i = 0; i < 38; ++i)
        gload_dw(battle + g + (uint32_t)(i * 256 + t), &dst[i * 256 + t]);
    };

    stagec(0, 0);                              // prologue prefetch

    for (int r = 0; r < 16; ++r) {
      if (r + 1 < 16) {
        stagec(r + 1, (r + 1) & 1);
        asm volatile("s_waitcnt vmcnt(38)" ::: "memory");  // row r ready, r+1 in flight
      } else {
        asm volatile("s_waitcnt vmcnt(0)" ::: "memory");
      }
      asm volatile("s_barrier" ::: "memory");

      const float* abuf = &shm[(r & 1) * 9728];
      f32x4 acc = {0.f, 0.f, 0.f, 0.f};
      #pragma unroll
      for (int si = 0; si < 12; ++si) {
        const int cs = wk * 12 + si;           // k = cs*32 + kg*8 (+0..7)
        const float* ap = abuf + abase + (uint32_t)(cs * 32 + kg * 8);
        f32x4 lo = *(const f32x4*)ap;
        f32x4 hi = *(const f32x4*)(ap + 4);
        short8 aa;
        aa[0] = (short)f2bf(lo[0]); aa[1] = (short)f2bf(lo[1]);
        aa[2] = (short)f2bf(lo[2]); aa[3] = (short)f2bf(lo[3]);
        aa[4] = (short)f2bf(hi[0]); aa[5] = (short)f2bf(hi[1]);
        aa[6] = (short)f2bf(hi[2]); aa[7] = (short)f2bf(hi[3]);
        short8 wf = *(const short8*)(wpack2 + (uint32_t)(cs * 512 + wn * 256 + kg * 64 + rl * 4));
        acc = __builtin_amdgcn_mfma_f32_16x16x32_bf16(aa, wf, acc, 0, 0, 0);
      }

      // reduce K-halves: wk=1 -> wred, barrier, wk=0 adds + stores
      if (wk == 1) {
        #pragma unroll
        for (int q = 0; q < 4; ++q)
          wred[wn * 256 + (kg * 4 + q) * 16 + rl] = acc[q];
      }
      asm volatile("s_barrier" ::: "memory");
      if (wk == 0) {
        const uint32_t ob = (uint32_t)(row0 + r) * 542u + 22u;
        #pragma unroll
        for (int q = 0; q < 4; ++q) {
          const int sub = kg * 4 + q;
          float v = acc[q] + wred[wn * 256 + (kg * 4 + q) * 16 + rl];
          if (sub < 13)
            out[ob + (uint32_t)(sub * 32 + wn * 16 + rl)] = v;
        }
      }
      // next iteration's post-stage barrier orders wred reuse
    }
    return;
  }

  // ======================= small-segment path (R5 structure) =======================
  const int sb = g9 * 5 + r9;                  // 0..2559
  int bloc, nsub, K, NOUT, soff, ooff;
  const float* wp;
  if (sb < 1280)      { bloc = sb;        nsub = 5; K = 101; NOUT = 16; soff = 9946; ooff = 462; wp = Wmonster; }
  else if (sb < 1536) { bloc = sb - 1280; nsub = 1; K = 180; NOUT = 16; soff = 9766; ooff = 446; wp = Wrelics; }
  else if (sb < 1792) { bloc = sb - 1536; nsub = 1; K = 86;  NOUT = 16; soff = 9;    ooff = 4;   wp = Wstatus; }
  else if (sb < 2048) { bloc = sb - 1792; nsub = 1; K = 43;  NOUT = 8;  soff = 9723; ooff = 438; wp = Wpotions; }
  else if (sb < 2304) { bloc = sb - 2048; nsub = 1; K = 9;   NOUT = 4;  soff = 0;    ooff = 0;   wp = Wplayer; }
  else                { bloc = sb - 2304; nsub = 1; K = 8;   NOUT = 2;  soff = 95;   ooff = 20;  wp = Wpinfo; }

  float* lds_a = shm;            // [128][32] fp32, 16B-granule XOR-swizzled
  float* lds_w = shm + 4096;     // [32][32]

  const int mb = bloc * 128;
  const int r0 = t >> 5;

  uint32_t rb[16];
  #pragma unroll
  for (int i = 0; i < 16; ++i) {
    uint32_t m   = (uint32_t)(mb + r0 + 8 * i);
    uint32_t b   = m / (uint32_t)nsub;
    uint32_t sub = m - b * (uint32_t)nsub;
    rb[i] = b * 10451u + (uint32_t)soff + sub * (uint32_t)K;
  }

  const int klin = t & 31;
  const int lk   = (((klin >> 2) ^ r0) << 2) | (klin & 3);

  f32x4 acc[2] = {};
  const int nch = (K + 31) >> 5;

  for (int ch = 0; ch < nch; ++ch) {
    const int kk = (ch << 5) + lk;
    #pragma unroll
    for (int i = 0; i < 16; ++i) {
      const float* sp = (kk < K) ? (battle + rb[i] + kk) : zpage;
      gload_dw(sp, &lds_a[i * 256 + t]);
    }
    #pragma unroll
    for (int i = 0; i < 4; ++i) {
      const int col = r0 + 8 * i;
      const float* sp = (col < NOUT && kk < K) ? (wp + col * K + kk) : zpage;
      gload_dw(sp, &lds_w[i * 256 + t]);
    }
    __syncthreads();

    short8 af[2], bfr;
    #pragma unroll
    for (int mf = 0; mf < 2; ++mf) {
      const int rr  = wv * 32 + mf * 16 + rl;
      const int g0i = (2 * kg) ^ (rr & 7);
      const int g1i = (2 * kg + 1) ^ (rr & 7);
      f32x4 lo = *(const f32x4*)&lds_a[rr * 32 + g0i * 4];
      f32x4 hi = *(const f32x4*)&lds_a[rr * 32 + g1i * 4];
      af[mf][0] = (short)f2bf(lo[0]); af[mf][1] = (short)f2bf(lo[1]);
      af[mf][2] = (short)f2bf(lo[2]); af[mf][3] = (short)f2bf(lo[3]);
      af[mf][4] = (short)f2bf(hi[0]); af[mf][5] = (short)f2bf(hi[1]);
      af[mf][6] = (short)f2bf(hi[2]); af[mf][7] = (short)f2bf(hi[3]);
    }
    {
      const int c   = rl;            // NOUT <= 16 for all small segments
      const int g0i = (2 * kg) ^ (c & 7);
      const int g1i = (2 * kg + 1) ^ (c & 7);
      f32x4 lo = *(const f32x4*)&lds_w[c * 32 + g0i * 4];
      f32x4 hi = *(const f32x4*)&lds_w[c * 32 + g1i * 4];
      bfr[0] = (short)f2bf(lo[0]); bfr[1] = (short)f2bf(lo[1]);
      bfr[2] = (short)f2bf(lo[2]); bfr[3] = (short)f2bf(lo[3]);
      bfr[4] = (short)f2bf(hi[0]); bfr[5] = (short)f2bf(hi[1]);
      bfr[6] = (short)f2bf(hi[2]); bfr[7] = (short)f2bf(hi[3]);
    }
    #pragma unroll
    for (int mf = 0; mf < 2; ++mf)
      acc[mf] = __builtin_amdgcn_mfma_f32_16x16x32_bf16(af[mf], bfr, acc[mf], 0, 0, 0);

    __syncthreads();
  }

  #pragma unroll
  for (int mf = 0; mf < 2; ++mf) {
    #pragma unroll
    for (int q = 0; q < 4; ++q) {
      uint32_t m   = (uint32_t)(mb + wv * 32 + mf * 16 + kg * 4 + q);
      uint32_t b   = m / (uint32_t)nsub;
      uint32_t sub = m - b * (uint32_t)nsub;
      uint32_t ob  = b * 542u + (uint32_t)ooff + sub * (uint32_t)NOUT;
      const int col = rl;
      if (col < NOUT) out[ob + col] = acc[mf][q];
    }
  }
}

extern "C" void kernel_launch(void* const* d_in, const int* in_sizes, int n_in,
                              void* d_out, int out_size, void* d_ws, size_t ws_size,
                              hipStream_t stream) {
  const float* battle   = (const float*)d_in[0];
  const float* Wplayer  = (const float*)d_in[1];
  const float* Wstatus  = (const float*)d_in[2];
  const float* Wpinfo   = (const float*)d_in[3];
  const float* Wcard    = (const float*)d_in[4];
  const float* Wpotions = (const float*)d_in[5];
  const float* Wrelics  = (const float*)d_in[6];
  const float* Wmonster = (const float*)d_in[7];
  float* out = (float*)d_out;

  // ws layout: [0,256) zero page | [256, 256+49152) frag-interleaved card W
  const float* zpage = (const float*)d_ws;
  uint32_t* wpack2 = (uint32_t*)((char*)d_ws + 256);

  hipMemsetAsync(d_ws, 0, 256, stream);
  hipLaunchKernelGGL(pack_w, dim3(48), dim3(256), 0, stream, Wcard, wpack2);
  hipLaunchKernelGGL(seg_gemm, dim3(4608), dim3(256), 0, stream,
                     battle, Wplayer, Wstatus, Wpinfo, Wpotions, Wrelics,
                     Wmonster, (const uint32_t*)wpack2, out, zpage);
}

// Round 7
// 299.892 us; speedup vs baseline: 1.2074x; 1.2074x over previous
//
#include <hip/hip_runtime.h>
#include <stdint.h>

// Segment layout (elements in each battle row of 10451 floats):
//  player 9 @0 | status 86 @9 | pinfo 8 @95 | 13 x card(740) @103 | potions 43 @9723
//  | relics 180 @9766 | 5 x monster(101) @9946
// Output row (542 floats): player4 @0 | status16 @4 | pinfo2 @20 | cards 13*32 @22
//  | potions8 @438 | relics16 @446 | monsters 5*16 @462
//
// R5 structure (best: 309us) + v_cvt_pk_bf16_f32 conversion (the serial
// compute phase was dominated by ~5-op integer f2bf per element; cvt_pk is 1
// op per 2 elements -> compute phase shrinks 3-4x, closing the stage/compute
// duty-cycle bubble). Card path: block = 2 battle rows staged as contiguous
// spans (no k-windows -> no sector overfetch), one barrier, MFMA from LDS.
// Small segments: windowed-LDS path (R1 structure).

typedef __attribute__((ext_vector_type(8))) short short8;
typedef __attribute__((ext_vector_type(4))) float f32x4;

__device__ inline unsigned short f2bf(float f) {
  union { float f; uint32_t u; } v; v.f = f;
  uint32_t r = v.u + 0x7FFFu + ((v.u >> 16) & 1u);   // round-to-nearest-even
  return (unsigned short)(r >> 16);
}

// packed bf16 pair via the HW converter (RNE), 1 VALU op for 2 elements
__device__ inline uint32_t cvt2(float lo, float hi) {
  uint32_t r;
  asm("v_cvt_pk_bf16_f32 %0, %1, %2" : "=v"(r) : "v"(lo), "v"(hi));
  return r;
}

union bfrag { short8 s; uint32_t u[4]; };

__device__ inline short8 mk_frag(f32x4 lo, f32x4 hi) {
  bfrag f;
  f.u[0] = cvt2(lo[0], lo[1]);
  f.u[1] = cvt2(lo[2], lo[3]);
  f.u[2] = cvt2(hi[0], hi[1]);
  f.u[3] = cvt2(hi[2], hi[3]);
  return f.s;
}

__device__ inline void gload_dw(const float* g, float* lds) {
  __builtin_amdgcn_global_load_lds(
      (const __attribute__((address_space(1))) void*)g,
      (__attribute__((address_space(3))) void*)lds, 4, 0, 0);
}

// Card W -> fragment-interleaved bf16: dword idx = cs*512 + wn*256 + kg*64 + rl*4 + d
// where cs (0..23) covers k = cs*32 + kg*8 + d*2; n = wn*16 + rl. Zero-padded
// beyond k=740. 12288 dwords = 48 KB.
__global__ __launch_bounds__(256) void pack_w(const float* __restrict__ Wc,
                                              uint32_t* __restrict__ wout) {
  int el = blockIdx.x * 256 + threadIdx.x;
  if (el >= 12288) return;
  int d  = el & 3;
  int rl = (el >> 2) & 15;
  int kg = (el >> 6) & 3;
  int wn = (el >> 8) & 1;
  int cs = el >> 9;
  int n  = wn * 16 + rl;
  int k  = cs * 32 + kg * 8 + d * 2;
  float v0 = (k     < 740) ? Wc[n * 740 + k]     : 0.0f;
  float v1 = (k + 1 < 740) ? Wc[n * 740 + k + 1] : 0.0f;
  wout[el] = (uint32_t)f2bf(v0) | ((uint32_t)f2bf(v1) << 16);
}

__global__ __launch_bounds__(256, 2) void seg_gemm(
    const float* __restrict__ battle,
    const float* __restrict__ Wplayer, const float* __restrict__ Wstatus,
    const float* __restrict__ Wpinfo,  const float* __restrict__ Wpotions,
    const float* __restrict__ Wrelics, const float* __restrict__ Wmonster,
    const uint32_t* __restrict__ wpack2,
    float* __restrict__ out, const float* __restrict__ zpage)
{
  __shared__ float shm[19456];   // 77824 B. card: [2][9728]; small: a[4096] + w[1024]
  const int bid  = blockIdx.x;
  const int t    = threadIdx.x;
  const int lane = t & 63;
  const int wv   = t >> 6;
  const int rl   = lane & 15;
  const int kg   = lane >> 4;

  if (bid < 16384) {
    // ======================= card path =======================
    const uint32_t g0 = (uint32_t)(bid * 2) * 10451u + 103u;
    const uint32_t g1 = g0 + 10451u;
    #pragma unroll
    for (int r = 0; r < 38; ++r)
      gload_dw(battle + g0 + (uint32_t)(r * 256 + t), &shm[r * 256 + t]);
    #pragma unroll
    for (int r = 0; r < 38; ++r)
      gload_dw(battle + g1 + (uint32_t)(r * 256 + t), &shm[9728 + r * 256 + t]);
    __syncthreads();   // compiler drains vmcnt(0); LDS read-only afterwards

    const int wm = wv >> 1;           // which battle row (span)
    const int wn = wv & 1;            // which n-half of the 32 outputs
    const float* aspan = &shm[wm * 9728];
    const uint32_t abase = (rl < 13) ? (uint32_t)(rl * 740) : 0u;  // dead rows -> word 0

    f32x4 acc = {0.f, 0.f, 0.f, 0.f};
    for (int ch = 0; ch < 6; ++ch) {
      #pragma unroll
      for (int s = 0; s < 4; ++s) {
        const float* ap = aspan + abase + (uint32_t)(ch * 128 + s * 32 + kg * 8);
        f32x4 lo = *(const f32x4*)ap;
        f32x4 hi = *(const f32x4*)(ap + 4);
        short8 aa = mk_frag(lo, hi);
        const int cs = ch * 4 + s;
        short8 wf = *(const short8*)(wpack2 + (uint32_t)(cs * 512 + wn * 256 + kg * 64 + rl * 4));
        acc = __builtin_amdgcn_mfma_f32_16x16x32_bf16(aa, wf, acc, 0, 0, 0);
      }
    }

    // C/D: col = lane&15 = rl (n), row = kg*4+q (sub). Rows 13..15 discarded.
    const uint32_t b = (uint32_t)(bid * 2 + wm);
    #pragma unroll
    for (int q = 0; q < 4; ++q) {
      const int sub = kg * 4 + q;
      if (sub < 13)
        out[b * 542u + 22u + (uint32_t)(sub * 32 + wn * 16 + rl)] = acc[q];
    }
    return;
  }

  // ======================= small-segment path (R1 structure) =======================
  const int sb = bid - 16384;
  int bloc, nsub, K, NOUT, soff, ooff;
  const float* wp;
  if (sb < 1280)      { bloc = sb;        nsub = 5; K = 101; NOUT = 16; soff = 9946; ooff = 462; wp = Wmonster; }
  else if (sb < 1536) { bloc = sb - 1280; nsub = 1; K = 180; NOUT = 16; soff = 9766; ooff = 446; wp = Wrelics; }
  else if (sb < 1792) { bloc = sb - 1536; nsub = 1; K = 86;  NOUT = 16; soff = 9;    ooff = 4;   wp = Wstatus; }
  else if (sb < 2048) { bloc = sb - 1792; nsub = 1; K = 43;  NOUT = 8;  soff = 9723; ooff = 438; wp = Wpotions; }
  else if (sb < 2304) { bloc = sb - 2048; nsub = 1; K = 9;   NOUT = 4;  soff = 0;    ooff = 0;   wp = Wplayer; }
  else                { bloc = sb - 2304; nsub = 1; K = 8;   NOUT = 2;  soff = 95;   ooff = 20;  wp = Wpinfo; }

  float* lds_a = shm;            // [128][32] fp32, 16B-granule XOR-swizzled
  float* lds_w = shm + 4096;     // [32][32]

  const int mb = bloc * 128;
  const int r0 = t >> 5;

  uint32_t rb[16];
  #pragma unroll
  for (int i = 0; i < 16; ++i) {
    uint32_t m   = (uint32_t)(mb + r0 + 8 * i);
    uint32_t b   = m / (uint32_t)nsub;
    uint32_t sub = m - b * (uint32_t)nsub;
    rb[i] = b * 10451u + (uint32_t)soff + sub * (uint32_t)K;
  }

  const int klin = t & 31;
  const int lk   = (((klin >> 2) ^ r0) << 2) | (klin & 3);

  f32x4 acc[2] = {};
  const int nch = (K + 31) >> 5;

  for (int ch = 0; ch < nch; ++ch) {
    const int kk = (ch << 5) + lk;
    #pragma unroll
    for (int i = 0; i < 16; ++i) {
      const float* sp = (kk < K) ? (battle + rb[i] + kk) : zpage;
      gload_dw(sp, &lds_a[i * 256 + t]);
    }
    #pragma unroll
    for (int i = 0; i < 4; ++i) {
      const int col = r0 + 8 * i;
      const float* sp = (col < NOUT && kk < K) ? (wp + col * K + kk) : zpage;
      gload_dw(sp, &lds_w[i * 256 + t]);
    }
    __syncthreads();

    short8 af[2], bfr;
    #pragma unroll
    for (int mf = 0; mf < 2; ++mf) {
      const int rr  = wv * 32 + mf * 16 + rl;
      const int g0i = (2 * kg) ^ (rr & 7);
      const int g1i = (2 * kg + 1) ^ (rr & 7);
      f32x4 lo = *(const f32x4*)&lds_a[rr * 32 + g0i * 4];
      f32x4 hi = *(const f32x4*)&lds_a[rr * 32 + g1i * 4];
      af[mf] = mk_frag(lo, hi);
    }
    {
      const int c   = rl;            // NOUT <= 16 for all small segments
      const int g0i = (2 * kg) ^ (c & 7);
      const int g1i = (2 * kg + 1) ^ (c & 7);
      f32x4 lo = *(const f32x4*)&lds_w[c * 32 + g0i * 4];
      f32x4 hi = *(const f32x4*)&lds_w[c * 32 + g1i * 4];
      bfr = mk_frag(lo, hi);
    }
    #pragma unroll
    for (int mf = 0; mf < 2; ++mf)
      acc[mf] = __builtin_amdgcn_mfma_f32_16x16x32_bf16(af[mf], bfr, acc[mf], 0, 0, 0);

    __syncthreads();
  }

  #pragma unroll
  for (int mf = 0; mf < 2; ++mf) {
    #pragma unroll
    for (int q = 0; q < 4; ++q) {
      uint32_t m   = (uint32_t)(mb + wv * 32 + mf * 16 + kg * 4 + q);
      uint32_t b   = m / (uint32_t)nsub;
      uint32_t sub = m - b * (uint32_t)nsub;
      uint32_t ob  = b * 542u + (uint32_t)ooff + sub * (uint32_t)NOUT;
      const int col = rl;
      if (col < NOUT) out[ob + col] = acc[mf][q];
    }
  }
}

extern "C" void kernel_launch(void* const* d_in, const int* in_sizes, int n_in,
                              void* d_out, int out_size, void* d_ws, size_t ws_size,
                              hipStream_t stream) {
  const float* battle   = (const float*)d_in[0];
  const float* Wplayer  = (const float*)d_in[1];
  const float* Wstatus  = (const float*)d_in[2];
  const float* Wpinfo   = (const float*)d_in[3];
  const float* Wcard    = (const float*)d_in[4];
  const float* Wpotions = (const float*)d_in[5];
  const float* Wrelics  = (const float*)d_in[6];
  const float* Wmonster = (const float*)d_in[7];
  float* out = (float*)d_out;

  // ws layout: [0,256) zero page | [256, 256+49152) frag-interleaved card W
  const float* zpage = (const float*)d_ws;
  uint32_t* wpack2 = (uint32_t*)((char*)d_ws + 256);

  hipMemsetAsync(d_ws, 0, 256, stream);
  hipLaunchKernelGGL(pack_w, dim3(48), dim3(256), 0, stream, Wcard, wpack2);
  hipLaunchKernelGGL(seg_gemm, dim3(18944), dim3(256), 0, stream,
                     battle, Wplayer, Wstatus, Wpinfo, Wpotions, Wrelics,
                     Wmonster, (const uint32_t*)wpack2, out, zpage);
}